// Round 1
// baseline (241.299 us; speedup 1.0000x reference)
//
#include <hip/hip_runtime.h>
#include <math.h>

#define D_ 512
#define S_ 50
#define M_ 20
#define BN_EPS_ 1e-5f

// Block-wide sum: 512 threads = 8 waves. Leading barrier makes back-to-back
// calls safe (prev read of red[] completes before next write).
__device__ __forceinline__ float block_reduce_sum(float v, float* red) {
    const int tid  = threadIdx.x;
    const int lane = tid & 63;
    const int wv   = tid >> 6;
    __syncthreads();
    #pragma unroll
    for (int off = 32; off; off >>= 1) v += __shfl_xor(v, off);
    if (lane == 0) red[wv] = v;
    __syncthreads();
    float x = red[0];
    #pragma unroll
    for (int w = 1; w < 8; ++w) x += red[w];
    return x;
}

__global__ __launch_bounds__(512) void fused_kernel(
    const float* __restrict__ img,    // [B,S,D]
    const float* __restrict__ tf,     // [M,2,D]
    const int*   __restrict__ rad,    // [B,M]
    const int*   __restrict__ vm,     // [B,S]
    const float* __restrict__ gamma,  // [2D]
    const float* __restrict__ beta,   // [2D]
    const float* __restrict__ mean,   // [2D]
    const float* __restrict__ var,    // [2D]
    const float* __restrict__ wcls,   // [2,2D]
    const float* __restrict__ bcls,   // [2]
    float*       __restrict__ out)    // [B,2]
{
    const int b    = blockIdx.x;
    const int tid  = threadIdx.x;
    const int lane = tid & 63;
    const int wv   = tid >> 6;

    __shared__ __align__(16) float t_lds[M_][D_];   // gathered+normalized text latents
    __shared__ __align__(16) float tbar[D_];
    __shared__ __align__(16) float accs[D_];        // imgsum (cross-wave)
    __shared__ __align__(16) float accp[D_];        // img_pool raw (cross-wave)
    __shared__ float attn_t[M_];
    __shared__ int   rad_s[M_];
    __shared__ int   msk[S_];
    __shared__ float red[8];
    __shared__ float cnt_inv_sh;

    // ---- tiny loads: mask (+count via ballot), rad indices; zero accumulators
    if (wv == 0) {
        int v = (lane < S_) ? vm[(size_t)b * S_ + lane] : 0;
        if (lane < S_) msk[lane] = v;
        unsigned long long bal = __ballot(v == 1);
        if (lane == 0) cnt_inv_sh = 1.0f / fmaxf((float)__popcll(bal), 1.0f);
    } else if (wv == 1) {
        if (lane < M_) rad_s[lane] = rad[(size_t)b * M_ + lane];
    }
    for (int i = tid; i < D_; i += 512) { accs[i] = 0.0f; accp[i] = 0.0f; }
    __syncthreads();

    // ---- stage gathered text rows into LDS (float4, coalesced; L2-resident source)
    {
        const float4* tf4 = (const float4*)tf;
        float4* tl4 = (float4*)(&t_lds[0][0]);
        #pragma unroll
        for (int i = tid; i < M_ * D_ / 4; i += 512) {
            int m  = i >> 7;         // 128 float4 per row
            int d4 = i & 127;
            tl4[i] = tf4[(size_t)(m * 2 + rad_s[m]) * (D_ / 4) + d4];
        }
    }
    __syncthreads();

    // ---- L2-normalize each text row in LDS (one row per wave, wave-level reduce)
    for (int m = wv; m < M_; m += 8) {
        float ss = 0.0f;
        #pragma unroll
        for (int j = 0; j < 8; ++j) {
            float x = t_lds[m][lane * 8 + j];
            ss += x * x;
        }
        #pragma unroll
        for (int off = 32; off; off >>= 1) ss += __shfl_xor(ss, off);
        float inv = 1.0f / sqrtf(ss);
        #pragma unroll
        for (int j = 0; j < 8; ++j) t_lds[m][lane * 8 + j] *= inv;
    }
    __syncthreads();

    // ---- tbar[d] = mean_m t[m][d]
    {
        float s = 0.0f;
        #pragma unroll
        for (int m = 0; m < M_; ++m) s += t_lds[m][tid];
        tbar[tid] = s * (1.0f / (float)M_);
    }
    __syncthreads();

    // hoist tbar slice into registers
    float tb[8];
    #pragma unroll
    for (int j = 0; j < 8; ++j) tb[j] = tbar[lane * 8 + j];

    // ---- main pass over valid image rows: one row per wave, strided
    float isum[8] = {0, 0, 0, 0, 0, 0, 0, 0};
    float ipool[8] = {0, 0, 0, 0, 0, 0, 0, 0};
    for (int s = wv; s < S_; s += 8) {
        if (msk[s] != 1) continue;  // masked rows are exactly zero -> skip the read
        const float4* p = (const float4*)(img + ((size_t)b * S_ + s) * D_) + lane * 2;
        float4 v0 = p[0];
        float4 v1 = p[1];
        float v[8] = {v0.x, v0.y, v0.z, v0.w, v1.x, v1.y, v1.z, v1.w};
        float ss = 0.0f, ar = 0.0f;
        #pragma unroll
        for (int j = 0; j < 8; ++j) {
            ss += v[j] * v[j];
            ar += tb[j] * v[j];
        }
        #pragma unroll
        for (int off = 32; off; off >>= 1) {
            ss += __shfl_xor(ss, off);
            ar += __shfl_xor(ar, off);
        }
        float inv = 1.0f / sqrtf(ss);          // l2norm of raw row
        float w2  = ar * inv * inv;            // attn_image[s] * inv (folds both scalings)
        #pragma unroll
        for (int j = 0; j < 8; ++j) {
            isum[j]  += v[j] * inv;            // imgsum  += normalized row
            ipool[j] += v[j] * w2;             // pool    += attn_image[s] * normalized row
        }
    }
    // combine wave partials
    #pragma unroll
    for (int j = 0; j < 8; ++j) {
        atomicAdd(&accs[lane * 8 + j], isum[j]);
        atomicAdd(&accp[lane * 8 + j], ipool[j]);
    }
    __syncthreads();

    // ---- img_pool L2 norm
    float pme = accp[tid];
    float ip_ss = block_reduce_sum(pme * pme, red);
    float inv_ip = 1.0f / sqrtf(ip_ss);

    // ---- attn_text[m] = (t[m] . imgsum) / cnt   (one m per wave, strided)
    for (int m = wv; m < M_; m += 8) {
        float d = 0.0f;
        #pragma unroll
        for (int j = 0; j < 8; ++j)
            d += t_lds[m][lane * 8 + j] * accs[lane * 8 + j];
        #pragma unroll
        for (int off = 32; off; off >>= 1) d += __shfl_xor(d, off);
        if (lane == 0) attn_t[m] = d * cnt_inv_sh;
    }
    __syncthreads();

    // ---- txt_pool[d] = sum_m attn_text[m] * t[m][d], then L2 norm
    float tp = 0.0f;
    #pragma unroll
    for (int m = 0; m < M_; ++m) tp += attn_t[m] * t_lds[m][tid];
    float tp_ss = block_reduce_sum(tp * tp, red);
    float inv_tp = 1.0f / sqrtf(tp_ss);

    // ---- ReLU -> BN(eval) -> linear [1024 -> 2]
    const int c1 = tid;        // image half channel
    const int c2 = D_ + tid;   // text half channel
    float h1 = fmaxf(pme * inv_ip, 0.0f);
    h1 = (h1 - mean[c1]) * (1.0f / sqrtf(var[c1] + BN_EPS_)) * gamma[c1] + beta[c1];
    float h2 = fmaxf(tp * inv_tp, 0.0f);
    h2 = (h2 - mean[c2]) * (1.0f / sqrtf(var[c2] + BN_EPS_)) * gamma[c2] + beta[c2];

    float o0 = h1 * wcls[c1] + h2 * wcls[c2];
    float o1 = h1 * wcls[2 * D_ + c1] + h2 * wcls[2 * D_ + c2];
    o0 = block_reduce_sum(o0, red);
    o1 = block_reduce_sum(o1, red);
    if (tid == 0) {
        out[(size_t)b * 2 + 0] = o0 + bcls[0];
        out[(size_t)b * 2 + 1] = o1 + bcls[1];
    }
}

extern "C" void kernel_launch(void* const* d_in, const int* in_sizes, int n_in,
                              void* d_out, int out_size, void* d_ws, size_t ws_size,
                              hipStream_t stream) {
    const float* img   = (const float*)d_in[0];
    const float* tf    = (const float*)d_in[1];
    const int*   rad   = (const int*)d_in[2];
    const int*   vmsk  = (const int*)d_in[3];
    const float* gamma = (const float*)d_in[4];
    const float* beta  = (const float*)d_in[5];
    const float* mean  = (const float*)d_in[6];
    const float* var   = (const float*)d_in[7];
    const float* wcls  = (const float*)d_in[8];
    const float* bcls  = (const float*)d_in[9];
    float* out = (float*)d_out;

    const int B = in_sizes[0] / (S_ * D_);  // 4096
    fused_kernel<<<B, 512, 0, stream>>>(img, tf, rad, vmsk, gamma, beta, mean, var,
                                        wcls, bcls, out);
}

// Round 3
// 220.011 us; speedup vs baseline: 1.0968x; 1.0968x over previous
//
#include <hip/hip_runtime.h>
#include <math.h>

#define D_ 512
#define S_ 50
#define M_ 20
#define BN_EPS_ 1e-5f

// ---------- DPP wave-wide sum (64 lanes). Result broadcast to all lanes via
// readlane(63). All VALU-pipe ops - no DS traffic. Controls are template
// params: __builtin_amdgcn_update_dpp requires constant integer args.
template <int CTRL, int RM>
__device__ __forceinline__ float dpp_step(float x) {
    int t = __builtin_amdgcn_update_dpp(0, __float_as_int(x), CTRL, RM, 0xf, true);
    return x + __int_as_float(t);
}
__device__ __forceinline__ float wave_sum(float x) {
    x = dpp_step<0x111, 0xf>(x);  // row_shr:1
    x = dpp_step<0x112, 0xf>(x);  // row_shr:2
    x = dpp_step<0x114, 0xf>(x);  // row_shr:4
    x = dpp_step<0x118, 0xf>(x);  // row_shr:8  -> lane15 of each row16 has row sum
    x = dpp_step<0x142, 0xa>(x);  // row_bcast:15 into rows 1,3
    x = dpp_step<0x143, 0xc>(x);  // row_bcast:31 into rows 2,3 -> lane63 = total
    return __int_as_float(__builtin_amdgcn_readlane(__float_as_int(x), 63));
}

// ---------- setup: normalize 40 text rows into ws; fold BN into classifier ----
__global__ __launch_bounds__(1024) void setup_kernel(
    const float* __restrict__ tf, const float* __restrict__ gamma,
    const float* __restrict__ beta, const float* __restrict__ mean,
    const float* __restrict__ var, const float* __restrict__ wcls,
    const float* __restrict__ bcls, float* __restrict__ ws)
{
    float* tnorm = ws;                 // [40][512]
    float* wf    = ws + 2 * M_ * D_;   // [2][1024]
    float* bf    = wf + 2 * 2 * D_;    // [2]
    const int tid  = threadIdx.x;
    const int lane = tid & 63;
    const int wv   = tid >> 6;         // 16 waves
    __shared__ float red0[16], red1[16];

    // A: L2-normalize each of the 40 raw text rows
    for (int row = wv; row < 2 * M_; row += 16) {
        const float4* p = (const float4*)(tf + (size_t)row * D_) + lane * 2;
        float4 a = p[0], b = p[1];
        float ss = a.x*a.x + a.y*a.y + a.z*a.z + a.w*a.w
                 + b.x*b.x + b.y*b.y + b.z*b.z + b.w*b.w;
        ss = wave_sum(ss);
        float inv = rsqrtf(ss);
        float4 na = {a.x*inv, a.y*inv, a.z*inv, a.w*inv};
        float4 nb = {b.x*inv, b.y*inv, b.z*inv, b.w*inv};
        float4* q = (float4*)(tnorm + (size_t)row * D_) + lane * 2;
        q[0] = na; q[1] = nb;
    }

    // B: BN fold: wf[k][c] = w[k][c]*scale[c]; bf[k] = b[k] + sum_c (beta-mean*scale)*w
    const int c = tid;  // 0..1023
    float s1 = rsqrtf(var[c] + BN_EPS_) * gamma[c];
    float w0 = wcls[c], w1 = wcls[2 * D_ + c];
    wf[c] = w0 * s1;
    wf[2 * D_ + c] = w1 * s1;
    float bmc = beta[c] - mean[c] * s1;
    float p0 = wave_sum(bmc * w0);
    float p1 = wave_sum(bmc * w1);
    if (lane == 0) { red0[wv] = p0; red1[wv] = p1; }
    __syncthreads();
    if (tid == 0) {
        float a = 0.f, b2 = 0.f;
        #pragma unroll
        for (int w = 0; w < 16; ++w) { a += red0[w]; b2 += red1[w]; }
        bf[0] = bcls[0] + a;
        bf[1] = bcls[1] + b2;
    }
}

// ---------- main: one block (8 waves) per batch element ----------
__global__ __launch_bounds__(512) void main_kernel(
    const float* __restrict__ img, const int* __restrict__ rad,
    const int* __restrict__ vm, const float* __restrict__ ws,
    float* __restrict__ out)
{
    const float* tnorm = ws;
    const float* wf    = ws + 2 * M_ * D_;
    const float* bf    = wf + 2 * 2 * D_;
    const int b    = blockIdx.x;
    const int tid  = threadIdx.x;
    const int lane = tid & 63;
    const int wv   = tid >> 6;

    __shared__ float tbarT[D_];    // transposed: tbarT[j*64+l] = tbar[8l+j]
    __shared__ float acc_s[D_];    // transposed imgsum
    __shared__ float acc_p[D_];    // transposed img_pool raw
    __shared__ float attn_arr[M_];
    __shared__ float redA[8], redB[8];

    acc_s[tid] = 0.f;
    acc_p[tid] = 0.f;

    // per-wave mask + count (duplicated per wave: no barrier, no LDS)
    int vmv = (lane < S_) ? vm[(size_t)b * S_ + lane] : 0;
    unsigned long long bal = __ballot(lane < S_ && vmv == 1);
    float cnt_inv = 1.0f / fmaxf((float)__popcll(bal), 1.0f);

    // ---- issue first two valid-row loads EARLY (overlap tbar phase)
    unsigned long long wbits = bal & (0x0101010101010101ULL << wv);
    int s0 = -1, s1 = -1;
    float4 a0{}, a1{}, b0{}, b1{};
    if (wbits) {
        s0 = __ffsll((unsigned long long)wbits) - 1; wbits &= wbits - 1;
        const float4* p = (const float4*)(img + ((size_t)b * S_ + s0) * D_) + lane * 2;
        a0 = p[0]; a1 = p[1];
    }
    if (wbits) {
        s1 = __ffsll((unsigned long long)wbits) - 1; wbits &= wbits - 1;
        const float4* p = (const float4*)(img + ((size_t)b * S_ + s1) * D_) + lane * 2;
        b0 = p[0]; b1 = p[1];
    }

    // ---- tbar (d-parallel, no reduction): thread t owns d = t
    {
        float s = 0.f;
        #pragma unroll
        for (int m = 0; m < M_; ++m) {
            int rm = rad[(size_t)b * M_ + m];          // uniform -> scalar load
            s += tnorm[(size_t)(2 * m + rm) * D_ + tid];
        }
        tbarT[(tid & 7) * 64 + (tid >> 3)] = s * (1.0f / (float)M_);
    }
    __syncthreads();  // 1

    float tb[8];
    #pragma unroll
    for (int j = 0; j < 8; ++j) tb[j] = tbarT[j * 64 + lane];  // conflict-free

    // ---- main loop over this wave's valid rows (2-deep pipeline, DPP reduces)
    float isum[8] = {0,0,0,0,0,0,0,0}, ipool[8] = {0,0,0,0,0,0,0,0};
    while (s0 >= 0) {
        float v[8] = {a0.x, a0.y, a0.z, a0.w, a1.x, a1.y, a1.z, a1.w};
        float ss = 0.f, ar = 0.f;
        #pragma unroll
        for (int j = 0; j < 8; ++j) { ss += v[j] * v[j]; ar += tb[j] * v[j]; }
        ss = wave_sum(ss);
        ar = wave_sum(ar);
        float inv = rsqrtf(ss);
        float w2  = ar * inv;
        #pragma unroll
        for (int j = 0; j < 8; ++j) {
            float vn = v[j] * inv;
            isum[j]  += vn;
            ipool[j] += vn * w2;
        }
        // rotate pipeline
        s0 = s1; a0 = b0; a1 = b1;
        s1 = -1;
        if (wbits) {
            s1 = __ffsll((unsigned long long)wbits) - 1; wbits &= wbits - 1;
            const float4* p = (const float4*)(img + ((size_t)b * S_ + s1) * D_) + lane * 2;
            b0 = p[0]; b1 = p[1];
        }
    }
    // cross-wave combine: transposed layout -> conflict-free LDS atomics
    #pragma unroll
    for (int j = 0; j < 8; ++j) {
        atomicAdd(&acc_s[j * 64 + lane], isum[j]);
        atomicAdd(&acc_p[j * 64 + lane], ipool[j]);
    }
    __syncthreads();  // 2

    // thread t owns d = t again
    float ap_ = acc_p[(tid & 7) * 64 + (tid >> 3)];

    float w_ip = wave_sum(ap_ * ap_);
    if (lane == 0) redA[wv] = w_ip;
    __syncthreads();  // 3
    float ip_ss = 0.f;
    #pragma unroll
    for (int w = 0; w < 8; ++w) ip_ss += redA[w];
    float inv_ip = rsqrtf(ip_ss);

    // ---- attn_text[m] = (tnorm[m] . imgsum) * cnt_inv
    float as8[8];
    #pragma unroll
    for (int j = 0; j < 8; ++j) as8[j] = acc_s[j * 64 + lane];  // conflict-free
    for (int m = wv; m < M_; m += 8) {
        int rm = rad[(size_t)b * M_ + m];
        const float4* p = (const float4*)(tnorm + (size_t)(2 * m + rm) * D_) + lane * 2;
        float4 ta = p[0], tb4 = p[1];
        float tv[8] = {ta.x, ta.y, ta.z, ta.w, tb4.x, tb4.y, tb4.z, tb4.w};
        float d = 0.f;
        #pragma unroll
        for (int j = 0; j < 8; ++j) d += tv[j] * as8[j];
        d = wave_sum(d);
        if (lane == 0) attn_arr[m] = d * cnt_inv;
    }
    __syncthreads();  // 4

    // ---- txt_pool (d-parallel) + norm
    float tp = 0.f;
    #pragma unroll
    for (int m = 0; m < M_; ++m) {
        int rm = rad[(size_t)b * M_ + m];
        tp += attn_arr[m] * tnorm[(size_t)(2 * m + rm) * D_ + tid];
    }
    float w_tp = wave_sum(tp * tp);
    if (lane == 0) redB[wv] = w_tp;
    __syncthreads();  // 5
    float tp_ss = 0.f;
    #pragma unroll
    for (int w = 0; w < 8; ++w) tp_ss += redB[w];
    float inv_tp = rsqrtf(tp_ss);

    // ---- ReLU -> folded BN+classifier [1024 -> 2]
    float h1 = fmaxf(ap_ * inv_ip, 0.f);
    float h2 = fmaxf(tp * inv_tp, 0.f);
    float o0 = h1 * wf[tid] + h2 * wf[D_ + tid];
    float o1 = h1 * wf[2 * D_ + tid] + h2 * wf[2 * D_ + D_ + tid];
    o0 = wave_sum(o0);
    o1 = wave_sum(o1);
    __syncthreads();  // 6: protect redA/redB reuse
    if (lane == 0) { redA[wv] = o0; redB[wv] = o1; }
    __syncthreads();  // 7
    if (tid == 0) {
        float x = 0.f, y = 0.f;
        #pragma unroll
        for (int w = 0; w < 8; ++w) { x += redA[w]; y += redB[w]; }
        out[(size_t)b * 2 + 0] = x + bf[0];
        out[(size_t)b * 2 + 1] = y + bf[1];
    }
}

extern "C" void kernel_launch(void* const* d_in, const int* in_sizes, int n_in,
                              void* d_out, int out_size, void* d_ws, size_t ws_size,
                              hipStream_t stream) {
    const float* img   = (const float*)d_in[0];
    const float* tf    = (const float*)d_in[1];
    const int*   rad   = (const int*)d_in[2];
    const int*   vmsk  = (const int*)d_in[3];
    const float* gamma = (const float*)d_in[4];
    const float* beta  = (const float*)d_in[5];
    const float* mean  = (const float*)d_in[6];
    const float* var   = (const float*)d_in[7];
    const float* wcls  = (const float*)d_in[8];
    const float* bcls  = (const float*)d_in[9];
    float* out = (float*)d_out;
    float* ws  = (float*)d_ws;

    const int B = in_sizes[0] / (S_ * D_);  // 4096

    setup_kernel<<<1, 1024, 0, stream>>>(tf, gamma, beta, mean, var, wcls, bcls, ws);
    main_kernel<<<B, 512, 0, stream>>>(img, rad, vmsk, ws, out);
}

// Round 4
// 70.987 us; speedup vs baseline: 3.3992x; 3.0993x over previous
//
#include <hip/hip_runtime.h>
#include <math.h>

#define D_ 512
#define S_ 50
#define M_ 20
#define BN_EPS_ 1e-5f

// ---------- DPP wave-wide sum (64 lanes), result broadcast via readlane(63).
// All VALU-pipe ops - no DS traffic. Controls must be constants -> template.
template <int CTRL, int RM>
__device__ __forceinline__ float dpp_step(float x) {
    int t = __builtin_amdgcn_update_dpp(0, __float_as_int(x), CTRL, RM, 0xf, true);
    return x + __int_as_float(t);
}
__device__ __forceinline__ float wave_sum(float x) {
    x = dpp_step<0x111, 0xf>(x);  // row_shr:1
    x = dpp_step<0x112, 0xf>(x);  // row_shr:2
    x = dpp_step<0x114, 0xf>(x);  // row_shr:4
    x = dpp_step<0x118, 0xf>(x);  // row_shr:8  -> lane15 of each row16 = row sum
    x = dpp_step<0x142, 0xa>(x);  // row_bcast:15 into rows 1,3
    x = dpp_step<0x143, 0xc>(x);  // row_bcast:31 into rows 2,3 -> lane63 = total
    return __int_as_float(__builtin_amdgcn_readlane(__float_as_int(x), 63));
}

// ---------- setup: normalize 40 text rows into ws; fold BN into classifier ----
__global__ __launch_bounds__(1024) void setup_kernel(
    const float* __restrict__ tf, const float* __restrict__ gamma,
    const float* __restrict__ beta, const float* __restrict__ mean,
    const float* __restrict__ var, const float* __restrict__ wcls,
    const float* __restrict__ bcls, float* __restrict__ ws)
{
    float* tnorm = ws;                 // [40][512]
    float* wf    = ws + 2 * M_ * D_;   // [2][1024]
    float* bf    = wf + 2 * 2 * D_;    // [2]
    const int tid  = threadIdx.x;
    const int lane = tid & 63;
    const int wv   = tid >> 6;         // 16 waves
    __shared__ float red0[16], red1[16];

    for (int row = wv; row < 2 * M_; row += 16) {
        const float4* p = (const float4*)(tf + (size_t)row * D_) + lane * 2;
        float4 a = p[0], b = p[1];
        float ss = a.x*a.x + a.y*a.y + a.z*a.z + a.w*a.w
                 + b.x*b.x + b.y*b.y + b.z*b.z + b.w*b.w;
        ss = wave_sum(ss);
        float inv = rsqrtf(ss);
        float4 na = {a.x*inv, a.y*inv, a.z*inv, a.w*inv};
        float4 nb = {b.x*inv, b.y*inv, b.z*inv, b.w*inv};
        float4* q = (float4*)(tnorm + (size_t)row * D_) + lane * 2;
        q[0] = na; q[1] = nb;
    }

    const int c = tid;  // 0..1023
    float s1 = rsqrtf(var[c] + BN_EPS_) * gamma[c];
    float w0 = wcls[c], w1 = wcls[2 * D_ + c];
    wf[c] = w0 * s1;
    wf[2 * D_ + c] = w1 * s1;
    float bmc = beta[c] - mean[c] * s1;
    float p0 = wave_sum(bmc * w0);
    float p1 = wave_sum(bmc * w1);
    if (lane == 0) { red0[wv] = p0; red1[wv] = p1; }
    __syncthreads();
    if (tid == 0) {
        float a = 0.f, b2 = 0.f;
        #pragma unroll
        for (int w = 0; w < 16; ++w) { a += red0[w]; b2 += red1[w]; }
        bf[0] = bcls[0] + a;
        bf[1] = bcls[1] + b2;
    }
}

// ---------- main: ONE WAVE per batch element. No LDS, no barriers. ----------
__global__ __launch_bounds__(256, 4) void main_kernel(
    const float* __restrict__ img, const int* __restrict__ rad,
    const int* __restrict__ vm, const float* __restrict__ ws,
    float* __restrict__ out, int B)
{
    const float* tnorm = ws;
    const float* wf    = ws + 2 * M_ * D_;
    const float* bf    = wf + 2 * 2 * D_;
    const int lane = threadIdx.x & 63;
    const int wv   = threadIdx.x >> 6;
    const int b    = blockIdx.x * 4 + wv;
    if (b >= B) return;

    // ---- tiny per-b loads, issued first: valid mask + rad vector
    int vmv  = (lane < S_) ? vm[(size_t)b * S_ + lane] : 0;
    int radv = (lane < M_) ? rad[(size_t)b * M_ + lane] : 0;
    unsigned long long bal = __ballot(lane < S_ && vmv == 1);
    float cnt_inv = 1.0f / fmaxf((float)__popcll(bal), 1.0f);

    // ---- 3-deep prefetch pipeline over valid image rows
    unsigned long long wb = bal;
    const float* imgb = img + (size_t)b * S_ * D_;
    int sA = -1, sB = -1, sC = -1;
    float4 A0{}, A1{}, B0{}, B1{}, C0{}, C1{};
    if (wb) {
        sA = __ffsll(wb) - 1; wb &= wb - 1;
        const float4* p = (const float4*)(imgb + (size_t)sA * D_) + lane * 2;
        A0 = p[0]; A1 = p[1];
    }
    if (wb) {
        sB = __ffsll(wb) - 1; wb &= wb - 1;
        const float4* p = (const float4*)(imgb + (size_t)sB * D_) + lane * 2;
        B0 = p[0]; B1 = p[1];
    }
    if (wb) {
        sC = __ffsll(wb) - 1; wb &= wb - 1;
        const float4* p = (const float4*)(imgb + (size_t)sC * D_) + lane * 2;
        C0 = p[0]; C1 = p[1];
    }

    // ---- tbar in registers (overlaps with in-flight img prefetch)
    float tb[8] = {0,0,0,0,0,0,0,0};
    #pragma unroll
    for (int m = 0; m < M_; ++m) {
        int rm = __builtin_amdgcn_readlane(radv, m);   // scalar, m const after unroll
        const float4* p = (const float4*)(tnorm + (size_t)(2 * m + rm) * D_) + lane * 2;
        float4 x = p[0], y = p[1];
        tb[0] += x.x; tb[1] += x.y; tb[2] += x.z; tb[3] += x.w;
        tb[4] += y.x; tb[5] += y.y; tb[6] += y.z; tb[7] += y.w;
    }
    #pragma unroll
    for (int j = 0; j < 8; ++j) tb[j] *= (1.0f / (float)M_);

    // ---- main pass: per row, ss = |v|^2 and ar = tbar.v via DPP wave sums
    float isum[8]  = {0,0,0,0,0,0,0,0};
    float ipool[8] = {0,0,0,0,0,0,0,0};
    while (sA >= 0) {
        float v[8] = {A0.x, A0.y, A0.z, A0.w, A1.x, A1.y, A1.z, A1.w};
        float ss = 0.f, ar = 0.f;
        #pragma unroll
        for (int j = 0; j < 8; ++j) { ss += v[j] * v[j]; ar += tb[j] * v[j]; }
        ss = wave_sum(ss);
        ar = wave_sum(ar);
        float inv = rsqrtf(ss);
        float w2  = ar * inv * inv;   // attn * inv folded
        #pragma unroll
        for (int j = 0; j < 8; ++j) {
            isum[j]  += v[j] * inv;
            ipool[j] += v[j] * w2;
        }
        sA = sB; A0 = B0; A1 = B1;
        sB = sC; B0 = C0; B1 = C1;
        sC = -1;
        if (wb) {
            sC = __ffsll(wb) - 1; wb &= wb - 1;
            const float4* p = (const float4*)(imgb + (size_t)sC * D_) + lane * 2;
            C0 = p[0]; C1 = p[1];
        }
    }

    // ---- img_pool norm
    float ipl = 0.f;
    #pragma unroll
    for (int j = 0; j < 8; ++j) ipl += ipool[j] * ipool[j];
    float inv_ip = rsqrtf(wave_sum(ipl));

    // ---- fused attn_text + txt_pool: each tnorm row read ONCE
    float tpool[8] = {0,0,0,0,0,0,0,0};
    #pragma unroll
    for (int m = 0; m < M_; ++m) {
        int rm = __builtin_amdgcn_readlane(radv, m);
        const float4* p = (const float4*)(tnorm + (size_t)(2 * m + rm) * D_) + lane * 2;
        float4 x = p[0], y = p[1];
        float tv[8] = {x.x, x.y, x.z, x.w, y.x, y.y, y.z, y.w};
        float d = 0.f;
        #pragma unroll
        for (int j = 0; j < 8; ++j) d += tv[j] * isum[j];
        float a = wave_sum(d) * cnt_inv;      // attn_text[m]
        #pragma unroll
        for (int j = 0; j < 8; ++j) tpool[j] += a * tv[j];
    }
    float tpl = 0.f;
    #pragma unroll
    for (int j = 0; j < 8; ++j) tpl += tpool[j] * tpool[j];
    float inv_tp = rsqrtf(wave_sum(tpl));

    // ---- ReLU -> folded BN+classifier [1024 -> 2], d = lane*8+j
    const float4* w00 = (const float4*)(wf)              + lane * 2;  // out0, img half
    const float4* w01 = (const float4*)(wf + D_)         + lane * 2;  // out0, txt half
    const float4* w10 = (const float4*)(wf + 2 * D_)     + lane * 2;  // out1, img half
    const float4* w11 = (const float4*)(wf + 3 * D_)     + lane * 2;  // out1, txt half
    float4 a0 = w00[0], a1 = w00[1], b0 = w01[0], b1 = w01[1];
    float4 c0 = w10[0], c1 = w10[1], d0 = w11[0], d1 = w11[1];
    float wA[8] = {a0.x,a0.y,a0.z,a0.w,a1.x,a1.y,a1.z,a1.w};
    float wB[8] = {b0.x,b0.y,b0.z,b0.w,b1.x,b1.y,b1.z,b1.w};
    float wC[8] = {c0.x,c0.y,c0.z,c0.w,c1.x,c1.y,c1.z,c1.w};
    float wD[8] = {d0.x,d0.y,d0.z,d0.w,d1.x,d1.y,d1.z,d1.w};
    float o0 = 0.f, o1 = 0.f;
    #pragma unroll
    for (int j = 0; j < 8; ++j) {
        float h1 = fmaxf(ipool[j] * inv_ip, 0.f);
        float h2 = fmaxf(tpool[j] * inv_tp, 0.f);
        o0 += h1 * wA[j] + h2 * wB[j];
        o1 += h1 * wC[j] + h2 * wD[j];
    }
    o0 = wave_sum(o0);
    o1 = wave_sum(o1);
    if (lane == 0) {
        float2 r = {o0 + bf[0], o1 + bf[1]};
        *(float2*)(out + (size_t)b * 2) = r;
    }
}

extern "C" void kernel_launch(void* const* d_in, const int* in_sizes, int n_in,
                              void* d_out, int out_size, void* d_ws, size_t ws_size,
                              hipStream_t stream) {
    const float* img   = (const float*)d_in[0];
    const float* tf    = (const float*)d_in[1];
    const int*   rad   = (const int*)d_in[2];
    const int*   vmsk  = (const int*)d_in[3];
    const float* gamma = (const float*)d_in[4];
    const float* beta  = (const float*)d_in[5];
    const float* mean  = (const float*)d_in[6];
    const float* var   = (const float*)d_in[7];
    const float* wcls  = (const float*)d_in[8];
    const float* bcls  = (const float*)d_in[9];
    float* out = (float*)d_out;
    float* ws  = (float*)d_ws;

    const int B = in_sizes[0] / (S_ * D_);  // 4096

    setup_kernel<<<1, 1024, 0, stream>>>(tf, gamma, beta, mean, var, wcls, bcls, ws);
    main_kernel<<<(B + 3) / 4, 256, 0, stream>>>(img, rad, vmsk, ws, out, B);
}

// Round 5
// 51.649 us; speedup vs baseline: 4.6719x; 1.3744x over previous
//
#include <hip/hip_runtime.h>
#include <math.h>

#define D_ 512
#define S_ 50
#define M_ 20
#define BN_EPS_ 1e-5f

// ---------- DPP wave-wide sum (64 lanes), result broadcast via readlane(63).
// All VALU-pipe ops - no DS traffic. Controls must be constants -> template.
template <int CTRL, int RM>
__device__ __forceinline__ float dpp_step(float x) {
    int t = __builtin_amdgcn_update_dpp(0, __float_as_int(x), CTRL, RM, 0xf, true);
    return x + __int_as_float(t);
}
__device__ __forceinline__ float wave_sum(float x) {
    x = dpp_step<0x111, 0xf>(x);  // row_shr:1
    x = dpp_step<0x112, 0xf>(x);  // row_shr:2
    x = dpp_step<0x114, 0xf>(x);  // row_shr:4
    x = dpp_step<0x118, 0xf>(x);  // row_shr:8  -> lane15 of each row16 = row sum
    x = dpp_step<0x142, 0xa>(x);  // row_bcast:15 into rows 1,3
    x = dpp_step<0x143, 0xc>(x);  // row_bcast:31 into rows 2,3 -> lane63 = total
    return __int_as_float(__builtin_amdgcn_readlane(__float_as_int(x), 63));
}

// ---------- setup (6 blocks): normalize 40 text rows; fold BN into classifier
__global__ __launch_bounds__(512) void setup_kernel(
    const float* __restrict__ tf, const float* __restrict__ gamma,
    const float* __restrict__ beta, const float* __restrict__ mean,
    const float* __restrict__ var, const float* __restrict__ wcls,
    const float* __restrict__ bcls, float* __restrict__ ws)
{
    float* tnorm = ws;                 // [40][512]
    float* wf    = ws + 2 * M_ * D_;   // [2][1024]
    float* bf    = wf + 4 * D_;        // [2]
    const int tid  = threadIdx.x;
    const int lane = tid & 63;
    const int wv   = tid >> 6;         // 8 waves

    if (blockIdx.x < 5) {
        // blocks 0..4: one text row per wave (40 rows total)
        const int row = blockIdx.x * 8 + wv;
        const float4* p = (const float4*)(tf + (size_t)row * D_) + lane * 2;
        float4 a = p[0], b = p[1];
        float ss = a.x*a.x + a.y*a.y + a.z*a.z + a.w*a.w
                 + b.x*b.x + b.y*b.y + b.z*b.z + b.w*b.w;
        ss = wave_sum(ss);
        float inv = rsqrtf(ss);
        float4 na = {a.x*inv, a.y*inv, a.z*inv, a.w*inv};
        float4 nb = {b.x*inv, b.y*inv, b.z*inv, b.w*inv};
        float4* q = (float4*)(tnorm + (size_t)row * D_) + lane * 2;
        q[0] = na; q[1] = nb;
    } else {
        // block 5: BN fold
        __shared__ float r0[8], r1[8];
        float pa = 0.f, pb = 0.f;
        for (int c = tid; c < 2 * D_; c += 512) {
            float s1 = rsqrtf(var[c] + BN_EPS_) * gamma[c];
            float w0 = wcls[c], w1 = wcls[2 * D_ + c];
            wf[c] = w0 * s1;
            wf[2 * D_ + c] = w1 * s1;
            float bmc = beta[c] - mean[c] * s1;
            pa += bmc * w0;
            pb += bmc * w1;
        }
        pa = wave_sum(pa);
        pb = wave_sum(pb);
        if (lane == 0) { r0[wv] = pa; r1[wv] = pb; }
        __syncthreads();
        if (tid == 0) {
            float A = 0.f, Bv = 0.f;
            #pragma unroll
            for (int w = 0; w < 8; ++w) { A += r0[w]; Bv += r1[w]; }
            bf[0] = bcls[0] + A;
            bf[1] = bcls[1] + Bv;
        }
    }
}

// ---------- main: FOUR waves per batch element (block = 256 = 1 b) ----------
__global__ __launch_bounds__(256, 4) void main_kernel(
    const float* __restrict__ img, const int* __restrict__ rad,
    const int* __restrict__ vm, const float* __restrict__ ws,
    float* __restrict__ out)
{
    const float* tnorm = ws;
    const float* wf    = ws + 2 * M_ * D_;
    const float* bf    = wf + 4 * D_;
    const int tid  = threadIdx.x;
    const int lane = tid & 63;
    const int wv   = tid >> 6;          // 0..3
    const int b    = blockIdx.x;

    // per-wave partial slots; layout [w][j*64+lane] -> all accesses are
    // lane-consecutive b32 (2-way aliasing = free)
    __shared__ float tbarP[4][D_];
    __shared__ float accS[4][D_];
    __shared__ float accP[4][D_];
    __shared__ float accT[4][D_];

    // ---- tiny per-b loads
    int vmv  = (lane < S_) ? vm[(size_t)b * S_ + lane] : 0;
    int radv = (lane < M_) ? rad[(size_t)b * M_ + lane] : 0;
    unsigned long long bal = __ballot(lane < S_ && vmv == 1);
    float cnt_inv = 1.0f / fmaxf((float)__popcll(bal), 1.0f);

    // this wave's image rows: s % 4 == wv
    unsigned long long wb = bal & (0x1111111111111111ULL << wv);
    const float* imgb = img + (size_t)b * S_ * D_;

    // ---- 3-deep prefetch, issued before the tbar phase (overlaps HBM latency)
    int sA = -1, sB = -1, sC = -1;
    float4 A0{}, A1{}, B0{}, B1{}, C0{}, C1{};
    if (wb) {
        sA = __ffsll(wb) - 1; wb &= wb - 1;
        const float4* p = (const float4*)(imgb + (size_t)sA * D_) + lane * 2;
        A0 = p[0]; A1 = p[1];
    }
    if (wb) {
        sB = __ffsll(wb) - 1; wb &= wb - 1;
        const float4* p = (const float4*)(imgb + (size_t)sB * D_) + lane * 2;
        B0 = p[0]; B1 = p[1];
    }
    if (wb) {
        sC = __ffsll(wb) - 1; wb &= wb - 1;
        const float4* p = (const float4*)(imgb + (size_t)sC * D_) + lane * 2;
        C0 = p[0]; C1 = p[1];
    }

    // ---- tbar partial over m = wv + 4k (5 rows per wave)
    float tbp[8] = {0,0,0,0,0,0,0,0};
    #pragma unroll
    for (int k = 0; k < M_ / 4; ++k) {
        int m  = wv + 4 * k;
        int rm = __builtin_amdgcn_readlane(radv, m);   // uniform lane idx (SGPR)
        const float4* p = (const float4*)(tnorm + (size_t)(2 * m + rm) * D_) + lane * 2;
        float4 x = p[0], y = p[1];
        tbp[0] += x.x; tbp[1] += x.y; tbp[2] += x.z; tbp[3] += x.w;
        tbp[4] += y.x; tbp[5] += y.y; tbp[6] += y.z; tbp[7] += y.w;
    }
    #pragma unroll
    for (int j = 0; j < 8; ++j) tbarP[wv][j * 64 + lane] = tbp[j];
    __syncthreads();  // 1

    float tb[8];
    #pragma unroll
    for (int j = 0; j < 8; ++j) {
        float s = tbarP[0][j * 64 + lane] + tbarP[1][j * 64 + lane]
                + tbarP[2][j * 64 + lane] + tbarP[3][j * 64 + lane];
        tb[j] = s * (1.0f / (float)M_);
    }

    // ---- image pass over this wave's rows (~6), DPP reductions
    float isum[8]  = {0,0,0,0,0,0,0,0};
    float ipool[8] = {0,0,0,0,0,0,0,0};
    while (sA >= 0) {
        float v[8] = {A0.x, A0.y, A0.z, A0.w, A1.x, A1.y, A1.z, A1.w};
        float ss = 0.f, ar = 0.f;
        #pragma unroll
        for (int j = 0; j < 8; ++j) { ss += v[j] * v[j]; ar += tb[j] * v[j]; }
        ss = wave_sum(ss);
        ar = wave_sum(ar);
        float inv = rsqrtf(ss);
        float w2  = ar * inv * inv;   // attn_image * inv, folded
        #pragma unroll
        for (int j = 0; j < 8; ++j) {
            isum[j]  += v[j] * inv;
            ipool[j] += v[j] * w2;
        }
        sA = sB; A0 = B0; A1 = B1;
        sB = sC; B0 = C0; B1 = C1;
        sC = -1;
        if (wb) {
            sC = __ffsll(wb) - 1; wb &= wb - 1;
            const float4* p = (const float4*)(imgb + (size_t)sC * D_) + lane * 2;
            C0 = p[0]; C1 = p[1];
        }
    }
    #pragma unroll
    for (int j = 0; j < 8; ++j) {
        accS[wv][j * 64 + lane] = isum[j];
        accP[wv][j * 64 + lane] = ipool[j];
    }
    __syncthreads();  // 2

    // combined imgsum, needed by every wave for the text dots
    float as8[8];
    #pragma unroll
    for (int j = 0; j < 8; ++j)
        as8[j] = accS[0][j * 64 + lane] + accS[1][j * 64 + lane]
               + accS[2][j * 64 + lane] + accS[3][j * 64 + lane];

    // ---- fused attn_text + txt_pool partial over m = wv + 4k
    float tpp[8] = {0,0,0,0,0,0,0,0};
    #pragma unroll
    for (int k = 0; k < M_ / 4; ++k) {
        int m  = wv + 4 * k;
        int rm = __builtin_amdgcn_readlane(radv, m);
        const float4* p = (const float4*)(tnorm + (size_t)(2 * m + rm) * D_) + lane * 2;
        float4 x = p[0], y = p[1];
        float tv[8] = {x.x, x.y, x.z, x.w, y.x, y.y, y.z, y.w};
        float d = 0.f;
        #pragma unroll
        for (int j = 0; j < 8; ++j) d += tv[j] * as8[j];
        float a = wave_sum(d) * cnt_inv;      // attn_text[m]
        #pragma unroll
        for (int j = 0; j < 8; ++j) tpp[j] += a * tv[j];
    }
    #pragma unroll
    for (int j = 0; j < 8; ++j) accT[wv][j * 64 + lane] = tpp[j];
    __syncthreads();  // 3

    // ---- tail: wave 0 only
    if (wv != 0) return;
    float ap8[8], tp8[8];
    float ipl = 0.f, tpl = 0.f;
    #pragma unroll
    for (int j = 0; j < 8; ++j) {
        ap8[j] = accP[0][j * 64 + lane] + accP[1][j * 64 + lane]
               + accP[2][j * 64 + lane] + accP[3][j * 64 + lane];
        tp8[j] = accT[0][j * 64 + lane] + accT[1][j * 64 + lane]
               + accT[2][j * 64 + lane] + accT[3][j * 64 + lane];
        ipl += ap8[j] * ap8[j];
        tpl += tp8[j] * tp8[j];
    }
    float inv_ip = rsqrtf(wave_sum(ipl));
    float inv_tp = rsqrtf(wave_sum(tpl));

    // ReLU -> folded BN+classifier [1024 -> 2], d = lane*8+j
    const float4* w00 = (const float4*)(wf)          + lane * 2;  // out0, img half
    const float4* w01 = (const float4*)(wf + D_)     + lane * 2;  // out0, txt half
    const float4* w10 = (const float4*)(wf + 2 * D_) + lane * 2;  // out1, img half
    const float4* w11 = (const float4*)(wf + 3 * D_) + lane * 2;  // out1, txt half
    float4 a0 = w00[0], a1 = w00[1], b0 = w01[0], b1 = w01[1];
    float4 c0 = w10[0], c1 = w10[1], d0 = w11[0], d1 = w11[1];
    float wA[8] = {a0.x,a0.y,a0.z,a0.w,a1.x,a1.y,a1.z,a1.w};
    float wB[8] = {b0.x,b0.y,b0.z,b0.w,b1.x,b1.y,b1.z,b1.w};
    float wC[8] = {c0.x,c0.y,c0.z,c0.w,c1.x,c1.y,c1.z,c1.w};
    float wD[8] = {d0.x,d0.y,d0.z,d0.w,d1.x,d1.y,d1.z,d1.w};
    float o0 = 0.f, o1 = 0.f;
    #pragma unroll
    for (int j = 0; j < 8; ++j) {
        float h1 = fmaxf(ap8[j] * inv_ip, 0.f);
        float h2 = fmaxf(tp8[j] * inv_tp, 0.f);
        o0 += h1 * wA[j] + h2 * wB[j];
        o1 += h1 * wC[j] + h2 * wD[j];
    }
    o0 = wave_sum(o0);
    o1 = wave_sum(o1);
    if (lane == 0) {
        float2 r = {o0 + bf[0], o1 + bf[1]};
        *(float2*)(out + (size_t)b * 2) = r;
    }
}

extern "C" void kernel_launch(void* const* d_in, const int* in_sizes, int n_in,
                              void* d_out, int out_size, void* d_ws, size_t ws_size,
                              hipStream_t stream) {
    const float* img   = (const float*)d_in[0];
    const float* tf    = (const float*)d_in[1];
    const int*   rad   = (const int*)d_in[2];
    const int*   vmsk  = (const int*)d_in[3];
    const float* gamma = (const float*)d_in[4];
    const float* beta  = (const float*)d_in[5];
    const float* mean  = (const float*)d_in[6];
    const float* var   = (const float*)d_in[7];
    const float* wcls  = (const float*)d_in[8];
    const float* bcls  = (const float*)d_in[9];
    float* out = (float*)d_out;
    float* ws  = (float*)d_ws;

    const int B = in_sizes[0] / (S_ * D_);  // 4096

    setup_kernel<<<6, 512, 0, stream>>>(tf, gamma, beta, mean, var, wcls, bcls, ws);
    main_kernel<<<B, 256, 0, stream>>>(img, rad, vmsk, ws, out);
}